// Round 11
// baseline (2026.233 us; speedup 1.0000x reference)
//
#include <hip/hip_runtime.h>
#include <math.h>

// B=256, T=2048, H=150. Sequential GRU, relu'd hidden, scalar linear head.
// 1 block / batch element (256 blocks = 256 CUs), 512 threads.
//
// R11 = R10 + 4-row broadcast amortization with BIT-EXACT association:
// the passing tree is ((a0+a1)+(a2+a3))+bhh, a_c = sequential stride-4
// chain. 4-way k-split BY CHAIN preserves it: wave quarter q (wid&3)
// computes chain a_q; thread owns rows 4idx..4idx+3 (idx=(wid>>2)*64+lane).
// Per k-elem: 1 v_readlane (h[4m+q] = hv component q, wave-uniform, of
// lane m) + s_mov dup (SALU, ~free) + 2 v_pk_fma (row pairs (r0,r1),(r2,r3),
// weights interleaved per k in v[100:251]). Per wave: 38 RL + 76 PK vs
// R10's 76 RL + 76 PK (RL=4cyc, PK=4cyc measured from R9/R10 VALUBusy).
// Phase-1 store: ONE conflict-free ds_write_b128 (4 consecutive rows),
// unconditional. Phase 2: ((p0+p1)+(p2+p3))+bhh -- same operands, same
// tree => bit-identical. Row 450 = W_lin (y); row 451 junk, never read;
// k>=150 pads multiply h[150..151]=0 (exact), loads clamped in-bounds.

#define BB 256
#define TT 2048
#define HH 150
#define H3 450

typedef float fx2 __attribute__((ext_vector_type(2)));

// Clobber list for explicit weight registers v100..v251.
#define WCLOB \
  "v100","v101","v102","v103","v104","v105","v106","v107","v108","v109", \
  "v110","v111","v112","v113","v114","v115","v116","v117","v118","v119", \
  "v120","v121","v122","v123","v124","v125","v126","v127","v128","v129", \
  "v130","v131","v132","v133","v134","v135","v136","v137","v138","v139", \
  "v140","v141","v142","v143","v144","v145","v146","v147","v148","v149", \
  "v150","v151","v152","v153","v154","v155","v156","v157","v158","v159", \
  "v160","v161","v162","v163","v164","v165","v166","v167","v168","v169", \
  "v170","v171","v172","v173","v174","v175","v176","v177","v178","v179", \
  "v180","v181","v182","v183","v184","v185","v186","v187","v188","v189", \
  "v190","v191","v192","v193","v194","v195","v196","v197","v198","v199", \
  "v200","v201","v202","v203","v204","v205","v206","v207","v208","v209", \
  "v210","v211","v212","v213","v214","v215","v216","v217","v218","v219", \
  "v220","v221","v222","v223","v224","v225","v226","v227","v228","v229", \
  "v230","v231","v232","v233","v234","v235","v236","v237","v238","v239", \
  "v240","v241","v242","v243","v244","v245","v246","v247","v248","v249", \
  "v250","v251"

// Load one k-slot (offset OFF = 16*m) for all 4 rows: A-pair (r0,r1),
// B-pair (r2,r3), interleaved per k.
#define LD4(vA0,vA1,vB0,vB1,OFF) \
  "global_load_dword v" #vA0 ", %[b0], off offset:" #OFF "\n\t" \
  "global_load_dword v" #vA1 ", %[b1], off offset:" #OFF "\n\t" \
  "global_load_dword v" #vB0 ", %[b2], off offset:" #OFF "\n\t" \
  "global_load_dword v" #vB1 ", %[b3], off offset:" #OFF "\n\t"

// 4 k-elems: 4 readlanes -> s20/22/24/26, SALU dups -> s21/23/25/27
// (>=4-inst WAR/RAW distance), then 8 pk_fmas (2 rows x 2 pairs each).
#define G4(m0,m1,m2,m3, A0,B0, A1,B1, A2,B2, A3,B3) \
  "v_readlane_b32 s20, %[hq], " #m0 "\n\t" \
  "v_readlane_b32 s22, %[hq], " #m1 "\n\t" \
  "v_readlane_b32 s24, %[hq], " #m2 "\n\t" \
  "v_readlane_b32 s26, %[hq], " #m3 "\n\t" \
  "s_mov_b32 s21, s20\n\t" \
  "s_mov_b32 s23, s22\n\t" \
  "s_mov_b32 s25, s24\n\t" \
  "s_mov_b32 s27, s26\n\t" \
  "v_pk_fma_f32 %[a01], s[20:21], " A0 ", %[a01]\n\t" \
  "v_pk_fma_f32 %[a23], s[20:21], " B0 ", %[a23]\n\t" \
  "v_pk_fma_f32 %[a01], s[22:23], " A1 ", %[a01]\n\t" \
  "v_pk_fma_f32 %[a23], s[22:23], " B1 ", %[a23]\n\t" \
  "v_pk_fma_f32 %[a01], s[24:25], " A2 ", %[a01]\n\t" \
  "v_pk_fma_f32 %[a23], s[24:25], " B2 ", %[a23]\n\t" \
  "v_pk_fma_f32 %[a01], s[26:27], " A3 ", %[a01]\n\t" \
  "v_pk_fma_f32 %[a23], s[26:27], " B3 ", %[a23]\n\t"

__global__ __launch_bounds__(512, 2) void gru_seq_kernel(
    const float* __restrict__ input,   // [B,T]
    const float* __restrict__ W_ih,    // [450,1]
    const float* __restrict__ W_hh,    // [450,150]
    const float* __restrict__ b_ih,    // [450]
    const float* __restrict__ b_hh,    // [450]
    const float* __restrict__ W_lin,   // [1,150]
    const float* __restrict__ b_lin,   // [1]
    float* __restrict__ out)           // [B,T]
{
    const int b    = blockIdx.x;
    const int tid  = threadIdx.x;
    const int lane = tid & 63;
    const int wid  = tid >> 6;               // 0..7
    const int q    = wid & 3;                // wave-uniform chain/quarter
    const int idx  = ((wid >> 2) << 6) + lane;   // 0..127

    __shared__ float  xrow[TT];        // 8 KB input row
    __shared__ float4 h4[64];          // h[0..149] zero-padded to 256 floats
    __shared__ float  pre[4 * 512];    // 8 KB: pre[q*512 + row], rows 0..511
    __shared__ float  yout[TT];        // 8 KB y buffer (no global ops in loop)

    // ---- prologue -------------------------------------------------------
    ((float4*)xrow)[tid] = ((const float4*)(input + (size_t)b * TT))[tid];
    if (tid < 64) h4[tid] = make_float4(0.f, 0.f, 0.f, 0.f);

    // Rows 4idx..4idx+3. Row 450 = W_lin (y-row). Row >=451: clamp to 449
    // (junk partials stored at pre[...][451..511], never read).
    const int r0 = 4 * idx, r1 = r0 + 1, r2 = r0 + 2, r3 = r0 + 3;
#define ROWP(r) ((r) == H3 ? W_lin : W_hh + ((r) < H3 ? (r) : (H3 - 1)) * HH)
    const float* b0 = ROWP(r0) + q;    // chain q: element k = 4m+q = b[16m bytes]
    const float* b1 = ROWP(r1) + q;
    const float* b2 = ROWP(r2) + q;
    const float* b3 = ROWP(r3) + q;

    // m = 0..36 into explicit regs (A-pair = v[100+2m], B-pair = v[176+2m]).
    asm volatile(
        LD4(100,101,176,177,0)    LD4(102,103,178,179,16)
        LD4(104,105,180,181,32)   LD4(106,107,182,183,48)
        LD4(108,109,184,185,64)   LD4(110,111,186,187,80)
        LD4(112,113,188,189,96)   LD4(114,115,190,191,112)
        LD4(116,117,192,193,128)  LD4(118,119,194,195,144)
        LD4(120,121,196,197,160)  LD4(122,123,198,199,176)
        LD4(124,125,200,201,192)  LD4(126,127,202,203,208)
        LD4(128,129,204,205,224)  LD4(130,131,206,207,240)
        LD4(132,133,208,209,256)  LD4(134,135,210,211,272)
        LD4(136,137,212,213,288)  LD4(138,139,214,215,304)
        LD4(140,141,216,217,320)  LD4(142,143,218,219,336)
        LD4(144,145,220,221,352)  LD4(146,147,222,223,368)
        LD4(148,149,224,225,384)  LD4(150,151,226,227,400)
        LD4(152,153,228,229,416)  LD4(154,155,230,231,432)
        LD4(156,157,232,233,448)  LD4(158,159,234,235,464)
        LD4(160,161,236,237,480)  LD4(162,163,238,239,496)
        LD4(164,165,240,241,512)  LD4(166,167,242,243,528)
        LD4(168,169,244,245,544)  LD4(170,171,246,247,560)
        LD4(172,173,248,249,576)
        "s_waitcnt vmcnt(0)\n\t"
        :
        : [b0] "v"(b0), [b1] "v"(b1), [b2] "v"(b2), [b3] "v"(b3)
        : WCLOB, "memory");
    // m = 37: k = 148+q. Real for q<2 (k=148,149); for q>=2 k=150,151 do
    // not exist -> their h is 0 (exact), so load any in-bounds junk (k=144+q).
    {
        const int t37 = (q < 2) ? 148 : 144;
        float w0 = b0[t37], w1 = b1[t37], w2 = b2[t37], w3 = b3[t37];
        asm volatile(
            "v_mov_b32 v174, %0\n\tv_mov_b32 v175, %1\n\t"
            "v_mov_b32 v250, %2\n\tv_mov_b32 v251, %3\n\t"
            :: "v"(w0), "v"(w1), "v"(w2), "v"(w3)
            : "v174","v175","v250","v251");
    }

    // Phase-2 constants (threads 0..149) -- verbatim from passing R10.
    float wih_r = 0.f, wih_z = 0.f, wih_n = 0.f;
    float bih_r = 0.f, bih_z = 0.f, bih_n = 0.f;
    float bhh_r = 0.f, bhh_z = 0.f, bhh_n = 0.f;
    if (tid < HH) {
        wih_r = W_ih[tid];          bih_r = b_ih[tid];          bhh_r = b_hh[tid];
        wih_z = W_ih[HH + tid];     bih_z = b_ih[HH + tid];     bhh_z = b_hh[HH + tid];
        wih_n = W_ih[2 * HH + tid]; bih_n = b_ih[2 * HH + tid]; bhh_n = b_hh[2 * HH + tid];
    }
    const float blin = b_lin[0];
    float hreg = 0.f;
    float* outb = out + (size_t)b * TT;
    float4* pst = (float4*)(pre + (q << 9) + (idx << 2));   // pre[q*512+4idx]

    __syncthreads();

    // ---- recurrence -----------------------------------------------------
    // Iteration t dots h_{t-1}; row 450 gives y_{t-1}. Extra iteration
    // t==TT supplies y_{TT-1}; its h-update is guarded off.
    for (int t = 0; t <= TT; ++t) {
        // phase 1: chain a_q of rows r0..r3. hv lane m holds h[4m..4m+3];
        // component q (wave-uniform) readlaned at lane m gives h[4m+q].
        float4 hv = h4[lane];
        float hq = (q == 0) ? hv.x : (q == 1) ? hv.y : (q == 2) ? hv.z : hv.w;
        fx2 a01; a01.x = 0.f; a01.y = 0.f;
        fx2 a23; a23.x = 0.f; a23.y = 0.f;
        asm volatile(
            G4( 0, 1, 2, 3, "v[100:101]","v[176:177]", "v[102:103]","v[178:179]",
                            "v[104:105]","v[180:181]", "v[106:107]","v[182:183]")
            G4( 4, 5, 6, 7, "v[108:109]","v[184:185]", "v[110:111]","v[186:187]",
                            "v[112:113]","v[188:189]", "v[114:115]","v[190:191]")
            G4( 8, 9,10,11, "v[116:117]","v[192:193]", "v[118:119]","v[194:195]",
                            "v[120:121]","v[196:197]", "v[122:123]","v[198:199]")
            G4(12,13,14,15, "v[124:125]","v[200:201]", "v[126:127]","v[202:203]",
                            "v[128:129]","v[204:205]", "v[130:131]","v[206:207]")
            G4(16,17,18,19, "v[132:133]","v[208:209]", "v[134:135]","v[210:211]",
                            "v[136:137]","v[212:213]", "v[138:139]","v[214:215]")
            G4(20,21,22,23, "v[140:141]","v[216:217]", "v[142:143]","v[218:219]",
                            "v[144:145]","v[220:221]", "v[146:147]","v[222:223]")
            G4(24,25,26,27, "v[148:149]","v[224:225]", "v[150:151]","v[226:227]",
                            "v[152:153]","v[228:229]", "v[154:155]","v[230:231]")
            G4(28,29,30,31, "v[156:157]","v[232:233]", "v[158:159]","v[234:235]",
                            "v[160:161]","v[236:237]", "v[162:163]","v[238:239]")
            G4(32,33,34,35, "v[164:165]","v[240:241]", "v[166:167]","v[242:243]",
                            "v[168:169]","v[244:245]", "v[170:171]","v[246:247]")
            // tail m=36,37 (s_nop pads the shorter RL->s_mov distance)
            "v_readlane_b32 s20, %[hq], 36\n\t"
            "v_readlane_b32 s22, %[hq], 37\n\t"
            "s_nop 3\n\t"
            "s_mov_b32 s21, s20\n\t"
            "s_mov_b32 s23, s22\n\t"
            "v_pk_fma_f32 %[a01], s[20:21], v[172:173], %[a01]\n\t"
            "v_pk_fma_f32 %[a23], s[20:21], v[248:249], %[a23]\n\t"
            "v_pk_fma_f32 %[a01], s[22:23], v[174:175], %[a01]\n\t"
            "v_pk_fma_f32 %[a23], s[22:23], v[250:251], %[a23]\n\t"
            : [a01] "+v"(a01), [a23] "+v"(a23)
            : [hq] "v"(hq)
            : "s20","s21","s22","s23","s24","s25","s26","s27", WCLOB);
        // One conflict-free b128 store: chain-q partials of rows 4idx..4idx+3.
        float4 st; st.x = a01.x; st.y = a01.y; st.z = a23.x; st.w = a23.y;
        *pst = st;
        __syncthreads();

        // phase 2: gates + hidden update (threads 0..149), skipped at t==TT.
        // pre_row = ((p0+p1)+(p2+p3)) + bhh -- same operands/tree as R10.
        if (t < TT && tid < HH) {
            float x  = xrow[t];
            float pr = ((pre[tid]        + pre[512 + tid])
                      + (pre[1024 + tid] + pre[1536 + tid]))        + bhh_r;
            float pz = ((pre[HH + tid]        + pre[512 + HH + tid])
                      + (pre[1024 + HH + tid] + pre[1536 + HH + tid])) + bhh_z;
            float pn = ((pre[2*HH + tid]        + pre[512 + 2*HH + tid])
                      + (pre[1024 + 2*HH + tid] + pre[1536 + 2*HH + tid])) + bhh_n;
            float gr = fmaf(x, wih_r, bih_r) + pr;
            float gz = fmaf(x, wih_z, bih_z) + pz;
            float r  = 1.f / (1.f + __expf(-gr));
            float z  = 1.f / (1.f + __expf(-gz));
            float ta = fmaf(x, wih_n, bih_n) + r * pn;
            ta = fminf(fmaxf(ta, -15.f), 15.f);
            float e  = __expf(2.f * ta);
            float n  = (e - 1.f) / (e + 1.f);        // tanh
            float hnew = fmaf(z, hreg - n, n);       // (1-z)*n + z*h
            hnew = fmaxf(hnew, 0.f);                 // relu
            hreg = hnew;
            ((float*)h4)[tid] = hnew;
        }
        // y_{t-1} from phase-1 row 450 (same tree as R10's (c01+c23)+blin).
        if (t > 0 && tid == H3) {
            yout[t - 1] = ((pre[H3]        + pre[512 + H3])
                         + (pre[1024 + H3] + pre[1536 + H3])) + blin;
        }
        __syncthreads();
    }

    // ---- epilogue: coalesced y dump (the loop's only global write) -------
    ((float4*)outb)[tid] = ((const float4*)yout)[tid];
}

extern "C" void kernel_launch(void* const* d_in, const int* in_sizes, int n_in,
                              void* d_out, int out_size, void* d_ws, size_t ws_size,
                              hipStream_t stream) {
    const float* input = (const float*)d_in[0];
    const float* W_ih  = (const float*)d_in[1];
    const float* W_hh  = (const float*)d_in[2];
    const float* b_ih  = (const float*)d_in[3];
    const float* b_hh  = (const float*)d_in[4];
    const float* W_lin = (const float*)d_in[5];
    const float* b_lin = (const float*)d_in[6];
    float* out = (float*)d_out;

    gru_seq_kernel<<<dim3(BB), dim3(512), 0, stream>>>(
        input, W_ih, W_hh, b_ih, b_hh, W_lin, b_lin, out);
}

// Round 12
// 1832.146 us; speedup vs baseline: 1.1059x; 1.1059x over previous
//
#include <hip/hip_runtime.h>
#include <math.h>

// B=256, T=2048, H=150. Sequential GRU, relu'd hidden, scalar linear head.
// 1 block / batch element (256 blocks = 256 CUs), 512 threads.
//
// R12 = R11's verified 4-row/chain-split structure (bit-exact association:
// wave quarter q computes stride-4 chain a_q for rows 4idx..4idx+3) with
// R11's two measured regressions removed:
//   1. s_mov SALU duplication -> op_sel broadcast: v_pk_fma_f32 with
//      op_sel:[0,0,0] op_sel_hi:[0,1,1] reads src0's LOW word for BOTH
//      packed lanes, so ONE v_readlane per k feeds 2 pk_fmas. No SALU,
//      no VALU->SALU->VALU hazard stalls (R11: VALUBusy fell 65->50 while
//      wall rose). Per wave: 38 RL + 76 PK.
//   2. ds_write_b128 (16B lane stride, 2.94e7 bank conflicts) -> two
//      ds_write_b64 at 8B lane stride (2-way alias = free) into
//      PPf[2][4][128] float2 layout; phase-2 reads via offset + q*1024B.
// Same operands, same ((q0+q1)+(q2+q3))+bhh tree => bit-identical.

#define BB 256
#define TT 2048
#define HH 150
#define H3 450

typedef float fx2 __attribute__((ext_vector_type(2)));

// Clobber list for explicit weight registers v100..v251.
#define WCLOB \
  "v100","v101","v102","v103","v104","v105","v106","v107","v108","v109", \
  "v110","v111","v112","v113","v114","v115","v116","v117","v118","v119", \
  "v120","v121","v122","v123","v124","v125","v126","v127","v128","v129", \
  "v130","v131","v132","v133","v134","v135","v136","v137","v138","v139", \
  "v140","v141","v142","v143","v144","v145","v146","v147","v148","v149", \
  "v150","v151","v152","v153","v154","v155","v156","v157","v158","v159", \
  "v160","v161","v162","v163","v164","v165","v166","v167","v168","v169", \
  "v170","v171","v172","v173","v174","v175","v176","v177","v178","v179", \
  "v180","v181","v182","v183","v184","v185","v186","v187","v188","v189", \
  "v190","v191","v192","v193","v194","v195","v196","v197","v198","v199", \
  "v200","v201","v202","v203","v204","v205","v206","v207","v208","v209", \
  "v210","v211","v212","v213","v214","v215","v216","v217","v218","v219", \
  "v220","v221","v222","v223","v224","v225","v226","v227","v228","v229", \
  "v230","v231","v232","v233","v234","v235","v236","v237","v238","v239", \
  "v240","v241","v242","v243","v244","v245","v246","v247","v248","v249", \
  "v250","v251"

// Load one k-slot (offset OFF = 16*m bytes) for all 4 rows.
#define LD4(vA0,vA1,vB0,vB1,OFF) \
  "global_load_dword v" #vA0 ", %[b0], off offset:" #OFF "\n\t" \
  "global_load_dword v" #vA1 ", %[b1], off offset:" #OFF "\n\t" \
  "global_load_dword v" #vB0 ", %[b2], off offset:" #OFF "\n\t" \
  "global_load_dword v" #vB1 ", %[b3], off offset:" #OFF "\n\t"

// pk_fma with src0-low broadcast to both packed lanes.
#define PKB(sp, vp, acc) \
  "v_pk_fma_f32 " acc ", " sp ", " vp ", " acc " op_sel:[0,0,0] op_sel_hi:[0,1,1]\n\t"

// 4 k-elems: 4 readlanes (even SGPRs only) then 8 broadcast-pk_fmas.
// First consumer of s20 is 4 insts after its write.
#define G4(m0,m1,m2,m3, A0,B0, A1,B1, A2,B2, A3,B3) \
  "v_readlane_b32 s20, %[hq], " #m0 "\n\t" \
  "v_readlane_b32 s22, %[hq], " #m1 "\n\t" \
  "v_readlane_b32 s24, %[hq], " #m2 "\n\t" \
  "v_readlane_b32 s26, %[hq], " #m3 "\n\t" \
  PKB("s[20:21]", A0, "%[a01]") PKB("s[20:21]", B0, "%[a23]") \
  PKB("s[22:23]", A1, "%[a01]") PKB("s[22:23]", B1, "%[a23]") \
  PKB("s[24:25]", A2, "%[a01]") PKB("s[24:25]", B2, "%[a23]") \
  PKB("s[26:27]", A3, "%[a01]") PKB("s[26:27]", B3, "%[a23]")

__global__ __launch_bounds__(512, 2) void gru_seq_kernel(
    const float* __restrict__ input,   // [B,T]
    const float* __restrict__ W_ih,    // [450,1]
    const float* __restrict__ W_hh,    // [450,150]
    const float* __restrict__ b_ih,    // [450]
    const float* __restrict__ b_hh,    // [450]
    const float* __restrict__ W_lin,   // [1,150]
    const float* __restrict__ b_lin,   // [1]
    float* __restrict__ out)           // [B,T]
{
    const int b    = blockIdx.x;
    const int tid  = threadIdx.x;
    const int lane = tid & 63;
    const int wid  = tid >> 6;               // 0..7
    const int q    = wid & 3;                // wave-uniform chain/quarter
    const int idx  = ((wid >> 2) << 6) + lane;   // 0..127

    __shared__ float  xrow[TT];        // 8 KB input row
    __shared__ float4 h4[64];          // h[0..149] zero-padded to 256 floats
    __shared__ float  PPf[2048];       // 8 KB partials:
                                       // [sel(=c>>1)*1024 + q*256 + g*2 + (c&1)]
    __shared__ float  yout[TT];        // 8 KB y buffer (no global ops in loop)

    // ---- prologue -------------------------------------------------------
    ((float4*)xrow)[tid] = ((const float4*)(input + (size_t)b * TT))[tid];
    if (tid < 64) h4[tid] = make_float4(0.f, 0.f, 0.f, 0.f);

    // Rows 4idx..4idx+3. Row 450 = W_lin (y-row). Row >=451: clamp to 449
    // (junk partials stored but never read).
    const int r0 = 4 * idx;
#define ROWP(r) ((r) == H3 ? W_lin : W_hh + ((r) < H3 ? (r) : (H3 - 1)) * HH)
    const float* b0 = ROWP(r0)     + q;   // chain q: element k = 4m+q
    const float* b1 = ROWP(r0 + 1) + q;
    const float* b2 = ROWP(r0 + 2) + q;
    const float* b3 = ROWP(r0 + 3) + q;

    // m = 0..36 into explicit regs (A-pair rows (r0,r1) = v[100+2m],
    // B-pair rows (r2,r3) = v[176+2m]).
    asm volatile(
        LD4(100,101,176,177,0)    LD4(102,103,178,179,16)
        LD4(104,105,180,181,32)   LD4(106,107,182,183,48)
        LD4(108,109,184,185,64)   LD4(110,111,186,187,80)
        LD4(112,113,188,189,96)   LD4(114,115,190,191,112)
        LD4(116,117,192,193,128)  LD4(118,119,194,195,144)
        LD4(120,121,196,197,160)  LD4(122,123,198,199,176)
        LD4(124,125,200,201,192)  LD4(126,127,202,203,208)
        LD4(128,129,204,205,224)  LD4(130,131,206,207,240)
        LD4(132,133,208,209,256)  LD4(134,135,210,211,272)
        LD4(136,137,212,213,288)  LD4(138,139,214,215,304)
        LD4(140,141,216,217,320)  LD4(142,143,218,219,336)
        LD4(144,145,220,221,352)  LD4(146,147,222,223,368)
        LD4(148,149,224,225,384)  LD4(150,151,226,227,400)
        LD4(152,153,228,229,416)  LD4(154,155,230,231,432)
        LD4(156,157,232,233,448)  LD4(158,159,234,235,464)
        LD4(160,161,236,237,480)  LD4(162,163,238,239,496)
        LD4(164,165,240,241,512)  LD4(166,167,242,243,528)
        LD4(168,169,244,245,544)  LD4(170,171,246,247,560)
        LD4(172,173,248,249,576)
        "s_waitcnt vmcnt(0)\n\t"
        :
        : [b0] "v"(b0), [b1] "v"(b1), [b2] "v"(b2), [b3] "v"(b3)
        : WCLOB, "memory");
    // m = 37: k = 148+q. Real for q<2; for q>=2 h[150..151]=0 (exact), so
    // load in-bounds junk (k=144+q) to avoid OOB.
    {
        const int t37 = (q < 2) ? 148 : 144;
        float w0 = b0[t37], w1 = b1[t37], w2 = b2[t37], w3 = b3[t37];
        asm volatile(
            "v_mov_b32 v174, %0\n\tv_mov_b32 v175, %1\n\t"
            "v_mov_b32 v250, %2\n\tv_mov_b32 v251, %3\n\t"
            :: "v"(w0), "v"(w1), "v"(w2), "v"(w3)
            : "v174","v175","v250","v251");
    }

    // Phase-2 constants (threads 0..149) -- verbatim from passing R10/R11.
    float wih_r = 0.f, wih_z = 0.f, wih_n = 0.f;
    float bih_r = 0.f, bih_z = 0.f, bih_n = 0.f;
    float bhh_r = 0.f, bhh_z = 0.f, bhh_n = 0.f;
    if (tid < HH) {
        wih_r = W_ih[tid];          bih_r = b_ih[tid];          bhh_r = b_hh[tid];
        wih_z = W_ih[HH + tid];     bih_z = b_ih[HH + tid];     bhh_z = b_hh[HH + tid];
        wih_n = W_ih[2 * HH + tid]; bih_n = b_ih[2 * HH + tid]; bhh_n = b_hh[2 * HH + tid];
    }
    const float blin = b_lin[0];
    float hreg = 0.f;
    float* outb = out + (size_t)b * TT;
    // Store pointers: float2 at 8B lane stride (conflict-free b64 writes).
    float2* st01 = (float2*)PPf          + (q << 7) + idx;   // sel 0
    float2* st23 = (float2*)(PPf + 1024) + (q << 7) + idx;   // sel 1
    // Phase-2 read indices (rows tid, 150+tid, 300+tid), chain offset +256.
    int ir = 0, iz = 0, in_ = 0;
    if (tid < HH) {
        int r;
        r = tid;        ir  = (((r & 3) >> 1) << 10) + ((r >> 2) << 1) + (r & 1);
        r = HH + tid;   iz  = (((r & 3) >> 1) << 10) + ((r >> 2) << 1) + (r & 1);
        r = 2*HH + tid; in_ = (((r & 3) >> 1) << 10) + ((r >> 2) << 1) + (r & 1);
    }
    const int iy = 1024 + (112 << 1);   // row 450: c=2,g=112

    __syncthreads();

    // ---- recurrence -----------------------------------------------------
    // Iteration t dots h_{t-1}; row 450 gives y_{t-1}. Extra iteration
    // t==TT supplies y_{TT-1}; its h-update is guarded off.
    for (int t = 0; t <= TT; ++t) {
        // phase 1: chain a_q of rows r0..r3. hv lane m holds h[4m..4m+3];
        // component q (wave-uniform) readlaned at lane m gives h[4m+q].
        float4 hv = h4[lane];
        float hq = (q == 0) ? hv.x : (q == 1) ? hv.y : (q == 2) ? hv.z : hv.w;
        fx2 a01; a01.x = 0.f; a01.y = 0.f;
        fx2 a23; a23.x = 0.f; a23.y = 0.f;
        asm volatile(
            G4( 0, 1, 2, 3, "v[100:101]","v[176:177]", "v[102:103]","v[178:179]",
                            "v[104:105]","v[180:181]", "v[106:107]","v[182:183]")
            G4( 4, 5, 6, 7, "v[108:109]","v[184:185]", "v[110:111]","v[186:187]",
                            "v[112:113]","v[188:189]", "v[114:115]","v[190:191]")
            G4( 8, 9,10,11, "v[116:117]","v[192:193]", "v[118:119]","v[194:195]",
                            "v[120:121]","v[196:197]", "v[122:123]","v[198:199]")
            G4(12,13,14,15, "v[124:125]","v[200:201]", "v[126:127]","v[202:203]",
                            "v[128:129]","v[204:205]", "v[130:131]","v[206:207]")
            G4(16,17,18,19, "v[132:133]","v[208:209]", "v[134:135]","v[210:211]",
                            "v[136:137]","v[212:213]", "v[138:139]","v[214:215]")
            G4(20,21,22,23, "v[140:141]","v[216:217]", "v[142:143]","v[218:219]",
                            "v[144:145]","v[220:221]", "v[146:147]","v[222:223]")
            G4(24,25,26,27, "v[148:149]","v[224:225]", "v[150:151]","v[226:227]",
                            "v[152:153]","v[228:229]", "v[154:155]","v[230:231]")
            G4(28,29,30,31, "v[156:157]","v[232:233]", "v[158:159]","v[234:235]",
                            "v[160:161]","v[236:237]", "v[162:163]","v[238:239]")
            // last 6 k-elems: 6 readlanes up front, then 12 pk_fmas.
            "v_readlane_b32 s20, %[hq], 32\n\t"
            "v_readlane_b32 s22, %[hq], 33\n\t"
            "v_readlane_b32 s24, %[hq], 34\n\t"
            "v_readlane_b32 s26, %[hq], 35\n\t"
            "v_readlane_b32 s28, %[hq], 36\n\t"
            "v_readlane_b32 s30, %[hq], 37\n\t"
            PKB("s[20:21]", "v[164:165]", "%[a01]")
            PKB("s[20:21]", "v[240:241]", "%[a23]")
            PKB("s[22:23]", "v[166:167]", "%[a01]")
            PKB("s[22:23]", "v[242:243]", "%[a23]")
            PKB("s[24:25]", "v[168:169]", "%[a01]")
            PKB("s[24:25]", "v[244:245]", "%[a23]")
            PKB("s[26:27]", "v[170:171]", "%[a01]")
            PKB("s[26:27]", "v[246:247]", "%[a23]")
            PKB("s[28:29]", "v[172:173]", "%[a01]")
            PKB("s[28:29]", "v[248:249]", "%[a23]")
            PKB("s[30:31]", "v[174:175]", "%[a01]")
            PKB("s[30:31]", "v[250:251]", "%[a23]")
            : [a01] "+v"(a01), [a23] "+v"(a23)
            : [hq] "v"(hq)
            : "s20","s22","s24","s26","s28","s30", WCLOB);
        // Two conflict-free b64 stores (8B lane stride).
        float2 s0; s0.x = a01.x; s0.y = a01.y;
        float2 s1; s1.x = a23.x; s1.y = a23.y;
        *st01 = s0;
        *st23 = s1;
        __syncthreads();

        // phase 2: gates + hidden update (threads 0..149), skipped at t==TT.
        // pre_row = ((q0+q1)+(q2+q3)) + bhh -- same operands/tree as R11.
        if (t < TT && tid < HH) {
            float x  = xrow[t];
            float pr = ((PPf[ir]        + PPf[ir + 256])
                      + (PPf[ir + 512]  + PPf[ir + 768]))  + bhh_r;
            float pz = ((PPf[iz]        + PPf[iz + 256])
                      + (PPf[iz + 512]  + PPf[iz + 768]))  + bhh_z;
            float pn = ((PPf[in_]       + PPf[in_ + 256])
                      + (PPf[in_ + 512] + PPf[in_ + 768])) + bhh_n;
            float gr = fmaf(x, wih_r, bih_r) + pr;
            float gz = fmaf(x, wih_z, bih_z) + pz;
            float r  = 1.f / (1.f + __expf(-gr));
            float z  = 1.f / (1.f + __expf(-gz));
            float ta = fmaf(x, wih_n, bih_n) + r * pn;
            ta = fminf(fmaxf(ta, -15.f), 15.f);
            float e  = __expf(2.f * ta);
            float n  = (e - 1.f) / (e + 1.f);        // tanh
            float hnew = fmaf(z, hreg - n, n);       // (1-z)*n + z*h
            hnew = fmaxf(hnew, 0.f);                 // relu
            hreg = hnew;
            ((float*)h4)[tid] = hnew;
        }
        // y_{t-1} from phase-1 row 450 (same tree).
        if (t > 0 && tid == H3) {
            yout[t - 1] = ((PPf[iy]       + PPf[iy + 256])
                         + (PPf[iy + 512] + PPf[iy + 768])) + blin;
        }
        __syncthreads();
    }

    // ---- epilogue: coalesced y dump (the loop's only global write) -------
    ((float4*)outb)[tid] = ((const float4*)yout)[tid];
}

extern "C" void kernel_launch(void* const* d_in, const int* in_sizes, int n_in,
                              void* d_out, int out_size, void* d_ws, size_t ws_size,
                              hipStream_t stream) {
    const float* input = (const float*)d_in[0];
    const float* W_ih  = (const float*)d_in[1];
    const float* W_hh  = (const float*)d_in[2];
    const float* b_ih  = (const float*)d_in[3];
    const float* b_hh  = (const float*)d_in[4];
    const float* W_lin = (const float*)d_in[5];
    const float* b_lin = (const float*)d_in[6];
    float* out = (float*)d_out;

    gru_seq_kernel<<<dim3(BB), dim3(512), 0, stream>>>(
        input, W_ih, W_hh, b_ih, b_hh, W_lin, b_lin, out);
}